// Round 7
// baseline (621.347 us; speedup 1.0000x reference)
//
#include <hip/hip_runtime.h>
#include <hip/hip_fp16.h>

// RGCN: out = hetero(relu(hetero(x, W1,b1)), W2,b2)
// Aggregation commutes with @W_r: Z[n] = [rs_in_r[n]*(sum_e rs_out_r[s]*feat[s] + self)]_r,
// layer = bias + Z(Nx384) @ W(384xWC).
// R7: (1) MFMA fp16 GEMM (A-frags straight from Z16 rows, B pre-repacked to lane
// layout); (2) gather split into 4x32-col slices keyed to XCD (blockIdx&3) so each
// XCD's slice (3.2MB) is L2-resident -> kills the ~50% miss rate on gathers.
// CSR build: radix partition, zero global atomics (device atomics ~32B fabric wr each).

constexpr int N   = 50000;
constexpr int R   = 3;
constexpr int IN  = 128;
constexpr int HID = 128;
constexpr int OUT = 64;
constexpr int M   = R * N;
constexpr int BK  = 1024;
constexpr int NBKT = (M + BK - 1) / BK;    // 147
constexpr int CHUNK = 8192;
constexpr int KB  = 24;                    // 384/16 k-blocks for MFMA

typedef _Float16 half8 __attribute__((ext_vector_type(8)));
typedef float floatx16 __attribute__((ext_vector_type(16)));

// ---- bias sums ----
__global__ void bsum_kernel(const float* __restrict__ b1, const float* __restrict__ b2,
                            float* __restrict__ bsum1, float* __restrict__ bsum2) {
    int t = threadIdx.x;
    if (t < HID) bsum1[t] = b1[t] + b1[HID + t] + b1[2 * HID + t];
    if (t < OUT) bsum2[t] = b2[t] + b2[OUT + t] + b2[2 * OUT + t];
}

// ---- fp32 -> fp16 convert ----
__global__ void cvt_kernel(const float4* __restrict__ in, uint2* __restrict__ out16, int n4) {
    int i = blockIdx.x * 256 + threadIdx.x;
    if (i >= n4) return;
    float4 v = in[i];
    __half2 a = __floats2half2_rn(v.x, v.y);
    __half2 b = __floats2half2_rn(v.z, v.w);
    uint2 o;
    o.x = *(unsigned*)&a;
    o.y = *(unsigned*)&b;
    out16[i] = o;
}

// ---- repack W1/W2 into MFMA B-fragment layout: frag[nt][kb][lane][j] with
// B[k=kb*16+(lane>>5)*8+j][col=nt*32+(lane&31)] ----
__global__ void wpack_kernel(const float* __restrict__ W1, const float* __restrict__ W2,
                             __half* __restrict__ F1, __half* __restrict__ F2) {
    int idx = blockIdx.x * 256 + threadIdx.x;     // frag id; 4*KB*64 + 2*KB*64 total
    if (idx < 4 * KB * 64) {
        int nt = idx / (KB * 64), rem = idx % (KB * 64);
        int kb = rem / 64, lane = rem % 64;
        int c = nt * 32 + (lane & 31);
        int k0 = kb * 16 + (lane >> 5) * 8;
        __half h[8];
#pragma unroll
        for (int j = 0; j < 8; j++) h[j] = __float2half_rn(W1[(k0 + j) * 128 + c]);
        *(uint4*)(F1 + (size_t)idx * 8) = *(uint4*)h;
    } else if (idx < 6 * KB * 64) {
        int i2 = idx - 4 * KB * 64;
        int nt = i2 / (KB * 64), rem = i2 % (KB * 64);
        int kb = rem / 64, lane = rem % 64;
        int c = nt * 32 + (lane & 31);
        int k0 = kb * 16 + (lane >> 5) * 8;
        __half h[8];
#pragma unroll
        for (int j = 0; j < 8; j++) h[j] = __float2half_rn(W2[(k0 + j) * 64 + c]);
        *(uint4*)(F2 + (size_t)i2 * 8) = *(uint4*)h;
    }
}

// ---- P1: coarse bucket histograms per edge-chunk ----
__global__ __launch_bounds__(256) void p1_kernel(const int* __restrict__ src,
                                                 const int* __restrict__ dst,
                                                 int E, int RE, int nb,
                                                 int* __restrict__ bh) {
    __shared__ int hd[NBKT], hs[NBKT];
    for (int i = threadIdx.x; i < NBKT; i += 256) { hd[i] = 0; hs[i] = 0; }
    __syncthreads();
    int beg = blockIdx.x * CHUNK, end = min(RE, beg + CHUNK);
    for (int g = beg + (int)threadIdx.x; g < end; g += 256) {
        int rb = ((g >= E) + (g >= 2 * E)) * N;
        atomicAdd(&hd[(rb + dst[g]) >> 10], 1);
        atomicAdd(&hs[(rb + src[g]) >> 10], 1);
    }
    __syncthreads();
    for (int i = threadIdx.x; i < NBKT; i += 256) {
        bh[i * nb + blockIdx.x] = hd[i];
        bh[(NBKT + i) * nb + blockIdx.x] = hs[i];
    }
}

// ---- 3-stage exclusive scan ----
__global__ void scan1_kernel(const int* __restrict__ in, int* __restrict__ out,
                             int* __restrict__ partials, int L) {
    __shared__ int lds[1024];
    int t = threadIdx.x;
    int idx = blockIdx.x * 1024 + t;
    int v = (idx < L) ? in[idx] : 0;
    lds[t] = v;
    __syncthreads();
    for (int off = 1; off < 1024; off <<= 1) {
        int u = (t >= off) ? lds[t - off] : 0;
        __syncthreads();
        lds[t] += u;
        __syncthreads();
    }
    if (idx < L) out[idx] = lds[t] - v;
    if (t == 1023) partials[blockIdx.x] = lds[1023];
}

__global__ void scan2_kernel(int* __restrict__ partials, int nb1) {
    __shared__ int lds[256];
    int t = threadIdx.x;
    int v = (t < nb1) ? partials[t] : 0;
    lds[t] = v;
    __syncthreads();
    for (int off = 1; off < 256; off <<= 1) {
        int u = (t >= off) ? lds[t - off] : 0;
        __syncthreads();
        lds[t] += u;
        __syncthreads();
    }
    if (t < nb1) partials[t] = lds[t] - v;
}

__global__ void scan3_kernel(int* __restrict__ out, const int* __restrict__ partials, int L) {
    int i = blockIdx.x * 256 + threadIdx.x;
    if (i < L) out[i] += partials[i >> 10];
}

// ---- P3: scatter edges into bucket-sorted buffers via LDS cursors ----
__global__ __launch_bounds__(256) void p3_kernel(const int* __restrict__ src,
                                                 const int* __restrict__ dst,
                                                 int E, int RE, int nb,
                                                 const int* __restrict__ scanv,
                                                 int* __restrict__ ebd,
                                                 int* __restrict__ ebs) {
    __shared__ int cd[NBKT], cs[NBKT];
    for (int i = threadIdx.x; i < NBKT; i += 256) {
        cd[i] = scanv[i * nb + blockIdx.x];
        cs[i] = scanv[(NBKT + i) * nb + blockIdx.x] - RE;
    }
    __syncthreads();
    int beg = blockIdx.x * CHUNK, end = min(RE, beg + CHUNK);
    for (int g = beg + (int)threadIdx.x; g < end; g += 256) {
        int rb = ((g >= E) + (g >= 2 * E)) * N;
        int s  = src[g];
        int kd = rb + dst[g];
        int pd = atomicAdd(&cd[kd >> 10], 1);
        ebd[pd] = (s << 10) | (kd & 1023);
        int ks = rb + s;
        int ps = atomicAdd(&cs[ks >> 10], 1);
        ebs[ps] = ks & 1023;
    }
}

// ---- PB: per bucket — exact histogram -> row_ptr/rs, then CSR scatter ----
__global__ __launch_bounds__(1024) void pb_kernel(const int* __restrict__ scanv, int nb, int RE,
                                                  const int* __restrict__ ebd,
                                                  const int* __restrict__ ebs,
                                                  int* __restrict__ row_ptr,
                                                  float* __restrict__ rs_in,
                                                  float* __restrict__ rs_out,
                                                  int* __restrict__ esrc) {
    __shared__ int cnt[BK];
    __shared__ int cur[BK];
    int t = threadIdx.x;
    bool dside = blockIdx.x < NBKT;
    int k = dside ? blockIdx.x : blockIdx.x - NBKT;
    int half = dside ? 0 : NBKT;
    int segbeg = scanv[(half + k) * nb];
    int segend = (k == NBKT - 1) ? (dside ? RE : 2 * RE) : scanv[(half + k + 1) * nb];
    if (!dside) { segbeg -= RE; segend -= RE; }
    cnt[t] = 0;
    __syncthreads();
    const int* __restrict__ eb = dside ? ebd : ebs;
    for (int e = segbeg + t; e < segend; e += 1024)
        atomicAdd(&cnt[eb[e] & 1023], 1);
    __syncthreads();
    int slot = k * BK + t;
    int c = cnt[t];
    if (dside) {
        cur[t] = c;
        __syncthreads();
        for (int off = 1; off < 1024; off <<= 1) {
            int u = (t >= off) ? cur[t - off] : 0;
            __syncthreads();
            cur[t] += u;
            __syncthreads();
        }
        int excl = cur[t] - c;
        if (slot < M) {
            row_ptr[slot] = segbeg + excl;
            rs_in[slot] = rsqrtf((float)(c + 1));
        }
        if (blockIdx.x == NBKT - 1 && t == 0) row_ptr[M] = RE;
        __syncthreads();
        cur[t] = segbeg + excl;
        __syncthreads();
        for (int e = segbeg + t; e < segend; e += 1024) {
            int v = eb[e];
            int pos = atomicAdd(&cur[v & 1023], 1);
            esrc[pos] = v >> 10;
        }
    } else {
        if (slot < M) rs_out[slot] = rsqrtf((float)(c + 1));
    }
}

// ---- pack per-edge coeff: esrc[i] = src | fp16(rs_out_r[src]) << 16 ----
__global__ void pack_kernel(unsigned int* __restrict__ esrc, const float* __restrict__ rs_out,
                            const int* __restrict__ row_ptr, int RE) {
    int i = blockIdx.x * 256 + threadIdx.x;
    if (i >= RE) return;
    int rp1 = row_ptr[N], rp2 = row_ptr[2 * N];
    int r = (i >= rp1) + (i >= rp2);
    unsigned s = esrc[i];
    __half h = __float2half_rn(rs_out[r * N + s]);
    esrc[i] = s | ((unsigned)__half_as_ushort(h) << 16);
}

// ---- XCD-split fused gather: split = blockIdx&3 -> cols [split*32, +32).
// Each XCD (blockIdx%8 round-robin) touches one 3.2MB feature slice -> L2-resident.
// Half-wave (32 lanes) per node; 1 fp16 col per lane; 64B line per gathered row.
__global__ __launch_bounds__(256) void gather_kernel(const __half* __restrict__ Xh,
                                                     const float* __restrict__ rs_in,
                                                     const float* __restrict__ rs_out,
                                                     const int* __restrict__ row_ptr,
                                                     const unsigned int* __restrict__ esrc,
                                                     __half* __restrict__ Z16) {
    int cb = (blockIdx.x & 3) * 32;
    int n  = (blockIdx.x >> 2) * 8 + (threadIdx.x >> 5);
    if (n >= N) return;
    int lane = threadIdx.x & 31;
    float xnv = __half2float(Xh[(long)n * 128 + cb + lane]);
#pragma unroll
    for (int r = 0; r < R; r++) {
        int key = r * N + n;
        float a = 0.f;
        int beg = row_ptr[key], end = row_ptr[key + 1];
        int e = beg;
        for (; e + 4 <= end; e += 4) {
            unsigned u0 = esrc[e], u1 = esrc[e + 1], u2 = esrc[e + 2], u3 = esrc[e + 3];
            float c0 = __half2float(__ushort_as_half((unsigned short)(u0 >> 16)));
            float c1 = __half2float(__ushort_as_half((unsigned short)(u1 >> 16)));
            float c2 = __half2float(__ushort_as_half((unsigned short)(u2 >> 16)));
            float c3 = __half2float(__ushort_as_half((unsigned short)(u3 >> 16)));
            float y0 = __half2float(Xh[(long)(u0 & 0xffffu) * 128 + cb + lane]);
            float y1 = __half2float(Xh[(long)(u1 & 0xffffu) * 128 + cb + lane]);
            float y2 = __half2float(Xh[(long)(u2 & 0xffffu) * 128 + cb + lane]);
            float y3 = __half2float(Xh[(long)(u3 & 0xffffu) * 128 + cb + lane]);
            a += c0 * y0 + c1 * y1 + c2 * y2 + c3 * y3;
        }
        for (; e < end; e++) {
            unsigned u = esrc[e];
            float c = __half2float(__ushort_as_half((unsigned short)(u >> 16)));
            a += c * __half2float(Xh[(long)(u & 0xffffu) * 128 + cb + lane]);
        }
        a += rs_out[key] * xnv;                        // self-loop
        Z16[(long)n * 384 + r * 128 + cb + lane] = __float2half_rn(rs_in[key] * a);
    }
}

// ---- MFMA GEMM: out[N,NT*32] = bias + Z16[N,384] @ W; A-frags direct from Z16
// rows (contiguous 16B per lane), B-frags from repacked F. 32x32x16 f16 MFMA.
// C/D map: col=lane&31, row=(reg&3)+8*(reg>>2)+4*(lane>>5)  [m74/m101 verified]
template <int NT, bool H16OUT>
__global__ __launch_bounds__(256) void mfma_gemm_kernel(const __half* __restrict__ Z16,
                                                        const __half* __restrict__ F,
                                                        const float* __restrict__ bias,
                                                        void* __restrict__ outp) {
    int wave = threadIdx.x >> 6, lane = threadIdx.x & 63;
    int m0 = blockIdx.x * 128 + wave * 32;
    int mrow = m0 + (lane & 31);
    int mr = min(mrow, N - 1);
    const half8* A = (const half8*)(Z16 + (long)mr * 384 + (lane >> 5) * 8);  // +2 per kb
    const half8* B = (const half8*)F;                                          // (nt*KB+kb)*64+lane
    floatx16 acc[NT];
#pragma unroll
    for (int i = 0; i < NT; i++)
#pragma unroll
        for (int j = 0; j < 16; j++) acc[i][j] = 0.f;

    half8 a = A[0];
    for (int kb = 0; kb < KB; kb++) {
        half8 an = (kb < KB - 1) ? A[(kb + 1) * 2] : a;
#pragma unroll
        for (int nt = 0; nt < NT; nt++) {
            half8 b = B[(nt * KB + kb) * 64 + lane];
            acc[nt] = __builtin_amdgcn_mfma_f32_32x32x16_f16(a, b, acc[nt], 0, 0, 0);
        }
        a = an;
    }

    float bv[NT];
#pragma unroll
    for (int nt = 0; nt < NT; nt++) bv[nt] = bias[nt * 32 + (lane & 31)];
    int rbase = m0 + 4 * (lane >> 5);
    int col0 = lane & 31;
#pragma unroll
    for (int nt = 0; nt < NT; nt++) {
#pragma unroll
        for (int reg = 0; reg < 16; reg++) {
            int row = rbase + (reg & 3) + 8 * (reg >> 2);
            if (row < N) {
                float v = acc[nt][reg] + bv[nt];
                if (H16OUT) {
                    v = fmaxf(v, 0.f);
                    ((__half*)outp)[(long)row * (NT * 32) + nt * 32 + col0] = __float2half_rn(v);
                } else {
                    ((float*)outp)[(long)row * (NT * 32) + nt * 32 + col0] = v;
                }
            }
        }
    }
}

extern "C" void kernel_launch(void* const* d_in, const int* in_sizes, int n_in,
                              void* d_out, int out_size, void* d_ws, size_t ws_size,
                              hipStream_t stream) {
    const float* x  = (const float*)d_in[0];
    const int*  src = (const int*)d_in[1];
    const int*  dst = (const int*)d_in[2];
    const float* W1 = (const float*)d_in[3];   // [384][128]
    const float* b1 = (const float*)d_in[4];
    const float* W2 = (const float*)d_in[5];   // [384][64]
    const float* b2 = (const float*)d_in[6];
    float* out = (float*)d_out;
    const int E  = in_sizes[1] / R;
    const int RE = in_sizes[1];
    const int nb = (RE + CHUNK - 1) / CHUNK;
    const int L  = 2 * NBKT * nb;
    const int nb1 = (L + 1023) / 1024;

    char* ws = (char*)d_ws;
    size_t off = 0;
    auto alloc = [&](size_t bytes) -> void* {
        void* p = ws + off;
        off += (bytes + 255) & ~(size_t)255;
        return p;
    };
    float* bsum1    = (float*)alloc(HID * 4);
    float* bsum2    = (float*)alloc(OUT * 4);
    float* rs_in    = (float*)alloc((size_t)M * 4);
    float* rs_out   = (float*)alloc((size_t)M * 4);
    int*   row_ptr  = (int*)alloc((size_t)(M + 1) * 4);
    int*   bh       = (int*)alloc((size_t)L * 4);
    int*   scanv    = (int*)alloc((size_t)L * 4);
    int*   partials = (int*)alloc((size_t)nb1 * 4);
    int*   esrc     = (int*)alloc((size_t)RE * 4);
    __half* F1      = (__half*)alloc((size_t)4 * KB * 64 * 8 * 2);
    __half* F2      = (__half*)alloc((size_t)2 * KB * 64 * 8 * 2);
    // region A: ebd+ebs (19.2MB) during build, Z16 (38.4MB) afterwards
    char*  regA     = (char*)alloc((size_t)N * 384 * 2);
    int*   ebd      = (int*)regA;
    int*   ebs      = (int*)(regA + (size_t)RE * 4);
    __half* Z16     = (__half*)regA;
    __half* x16     = (__half*)alloc((size_t)N * IN * 2);
    __half* H16     = (__half*)alloc((size_t)N * HID * 2);

    bsum_kernel<<<1, 128, 0, stream>>>(b1, b2, bsum1, bsum2);
    cvt_kernel<<<(N * IN / 4 + 255) / 256, 256, 0, stream>>>(
        (const float4*)x, (uint2*)x16, N * IN / 4);
    wpack_kernel<<<(6 * KB * 64 + 255) / 256, 256, 0, stream>>>(W1, W2, F1, F2);
    p1_kernel<<<nb, 256, 0, stream>>>(src, dst, E, RE, nb, bh);
    scan1_kernel<<<nb1, 1024, 0, stream>>>(bh, scanv, partials, L);
    scan2_kernel<<<1, 256, 0, stream>>>(partials, nb1);
    scan3_kernel<<<(L + 255) / 256, 256, 0, stream>>>(scanv, partials, L);
    p3_kernel<<<nb, 256, 0, stream>>>(src, dst, E, RE, nb, scanv, ebd, ebs);
    pb_kernel<<<2 * NBKT, 1024, 0, stream>>>(scanv, nb, RE, ebd, ebs,
                                             row_ptr, rs_in, rs_out, esrc);
    pack_kernel<<<(RE + 255) / 256, 256, 0, stream>>>(
        (unsigned int*)esrc, rs_out, row_ptr, RE);

    const int gab = ((N + 7) / 8) * 4;        // 25000 gather blocks (4 splits)
    const int ggb = (N + 127) / 128;          // 391 gemm blocks

    // layer 1: Z = gather(x16); H16 = fp16(relu(bsum1 + Z @ W1))
    gather_kernel<<<gab, 256, 0, stream>>>(x16, rs_in, rs_out, row_ptr,
                                           (const unsigned int*)esrc, Z16);
    mfma_gemm_kernel<4, true><<<ggb, 256, 0, stream>>>(Z16, F1, bsum1, H16);
    // layer 2: Z = gather(H16); out = bsum2 + Z @ W2
    gather_kernel<<<gab, 256, 0, stream>>>(H16, rs_in, rs_out, row_ptr,
                                           (const unsigned int*)esrc, Z16);
    mfma_gemm_kernel<2, false><<<ggb, 256, 0, stream>>>(Z16, F2, bsum2, out);
}

// Round 8
// 423.311 us; speedup vs baseline: 1.4678x; 1.4678x over previous
//
#include <hip/hip_runtime.h>
#include <hip/hip_fp16.h>

// RGCN: out = hetero(relu(hetero(x, W1,b1)), W2,b2)
// Aggregation commutes with @W_r: Z[n] = [rs_in_r[n]*(sum_e rs_out_r[s]*feat[s] + self)]_r,
// layer = bias + Z(Nx384) @ W(384xWC).
// R8 = R6 gather (full-wave, 256B fp16 rows — R7's XCD-split gather was
// issue-bound, 2x slower) + R7 MFMA fp16 GEMM (A-frags direct from Z16 rows,
// B pre-repacked; replaced the 119us VALU GEMM with ~20us MFMA).
// CSR build: radix partition, zero global atomics (device atomics ~32B fabric wr each).

constexpr int N   = 50000;
constexpr int R   = 3;
constexpr int IN  = 128;
constexpr int HID = 128;
constexpr int OUT = 64;
constexpr int M   = R * N;
constexpr int BK  = 1024;
constexpr int NBKT = (M + BK - 1) / BK;    // 147
constexpr int CHUNK = 8192;
constexpr int KB  = 24;                    // 384/16 k-blocks for MFMA

typedef _Float16 half8 __attribute__((ext_vector_type(8)));
typedef float floatx16 __attribute__((ext_vector_type(16)));

// ---- bias sums ----
__global__ void bsum_kernel(const float* __restrict__ b1, const float* __restrict__ b2,
                            float* __restrict__ bsum1, float* __restrict__ bsum2) {
    int t = threadIdx.x;
    if (t < HID) bsum1[t] = b1[t] + b1[HID + t] + b1[2 * HID + t];
    if (t < OUT) bsum2[t] = b2[t] + b2[OUT + t] + b2[2 * OUT + t];
}

// ---- fp32 -> fp16 convert ----
__global__ void cvt_kernel(const float4* __restrict__ in, uint2* __restrict__ out16, int n4) {
    int i = blockIdx.x * 256 + threadIdx.x;
    if (i >= n4) return;
    float4 v = in[i];
    __half2 a = __floats2half2_rn(v.x, v.y);
    __half2 b = __floats2half2_rn(v.z, v.w);
    uint2 o;
    o.x = *(unsigned*)&a;
    o.y = *(unsigned*)&b;
    out16[i] = o;
}

// ---- repack W1/W2 into MFMA B-fragment layout: frag[nt][kb][lane][j] with
// B[k=kb*16+(lane>>5)*8+j][col=nt*32+(lane&31)] ----
__global__ void wpack_kernel(const float* __restrict__ W1, const float* __restrict__ W2,
                             __half* __restrict__ F1, __half* __restrict__ F2) {
    int idx = blockIdx.x * 256 + threadIdx.x;     // frag id; 4*KB*64 + 2*KB*64 total
    if (idx < 4 * KB * 64) {
        int nt = idx / (KB * 64), rem = idx % (KB * 64);
        int kb = rem / 64, lane = rem % 64;
        int c = nt * 32 + (lane & 31);
        int k0 = kb * 16 + (lane >> 5) * 8;
        __half h[8];
#pragma unroll
        for (int j = 0; j < 8; j++) h[j] = __float2half_rn(W1[(k0 + j) * 128 + c]);
        *(uint4*)(F1 + (size_t)idx * 8) = *(uint4*)h;
    } else if (idx < 6 * KB * 64) {
        int i2 = idx - 4 * KB * 64;
        int nt = i2 / (KB * 64), rem = i2 % (KB * 64);
        int kb = rem / 64, lane = rem % 64;
        int c = nt * 32 + (lane & 31);
        int k0 = kb * 16 + (lane >> 5) * 8;
        __half h[8];
#pragma unroll
        for (int j = 0; j < 8; j++) h[j] = __float2half_rn(W2[(k0 + j) * 64 + c]);
        *(uint4*)(F2 + (size_t)i2 * 8) = *(uint4*)h;
    }
}

// ---- P1: coarse bucket histograms per edge-chunk ----
__global__ __launch_bounds__(256) void p1_kernel(const int* __restrict__ src,
                                                 const int* __restrict__ dst,
                                                 int E, int RE, int nb,
                                                 int* __restrict__ bh) {
    __shared__ int hd[NBKT], hs[NBKT];
    for (int i = threadIdx.x; i < NBKT; i += 256) { hd[i] = 0; hs[i] = 0; }
    __syncthreads();
    int beg = blockIdx.x * CHUNK, end = min(RE, beg + CHUNK);
    for (int g = beg + (int)threadIdx.x; g < end; g += 256) {
        int rb = ((g >= E) + (g >= 2 * E)) * N;
        atomicAdd(&hd[(rb + dst[g]) >> 10], 1);
        atomicAdd(&hs[(rb + src[g]) >> 10], 1);
    }
    __syncthreads();
    for (int i = threadIdx.x; i < NBKT; i += 256) {
        bh[i * nb + blockIdx.x] = hd[i];
        bh[(NBKT + i) * nb + blockIdx.x] = hs[i];
    }
}

// ---- 3-stage exclusive scan ----
__global__ void scan1_kernel(const int* __restrict__ in, int* __restrict__ out,
                             int* __restrict__ partials, int L) {
    __shared__ int lds[1024];
    int t = threadIdx.x;
    int idx = blockIdx.x * 1024 + t;
    int v = (idx < L) ? in[idx] : 0;
    lds[t] = v;
    __syncthreads();
    for (int off = 1; off < 1024; off <<= 1) {
        int u = (t >= off) ? lds[t - off] : 0;
        __syncthreads();
        lds[t] += u;
        __syncthreads();
    }
    if (idx < L) out[idx] = lds[t] - v;
    if (t == 1023) partials[blockIdx.x] = lds[1023];
}

__global__ void scan2_kernel(int* __restrict__ partials, int nb1) {
    __shared__ int lds[256];
    int t = threadIdx.x;
    int v = (t < nb1) ? partials[t] : 0;
    lds[t] = v;
    __syncthreads();
    for (int off = 1; off < 256; off <<= 1) {
        int u = (t >= off) ? lds[t - off] : 0;
        __syncthreads();
        lds[t] += u;
        __syncthreads();
    }
    if (t < nb1) partials[t] = lds[t] - v;
}

__global__ void scan3_kernel(int* __restrict__ out, const int* __restrict__ partials, int L) {
    int i = blockIdx.x * 256 + threadIdx.x;
    if (i < L) out[i] += partials[i >> 10];
}

// ---- P3: scatter edges into bucket-sorted buffers via LDS cursors ----
__global__ __launch_bounds__(256) void p3_kernel(const int* __restrict__ src,
                                                 const int* __restrict__ dst,
                                                 int E, int RE, int nb,
                                                 const int* __restrict__ scanv,
                                                 int* __restrict__ ebd,
                                                 int* __restrict__ ebs) {
    __shared__ int cd[NBKT], cs[NBKT];
    for (int i = threadIdx.x; i < NBKT; i += 256) {
        cd[i] = scanv[i * nb + blockIdx.x];
        cs[i] = scanv[(NBKT + i) * nb + blockIdx.x] - RE;
    }
    __syncthreads();
    int beg = blockIdx.x * CHUNK, end = min(RE, beg + CHUNK);
    for (int g = beg + (int)threadIdx.x; g < end; g += 256) {
        int rb = ((g >= E) + (g >= 2 * E)) * N;
        int s  = src[g];
        int kd = rb + dst[g];
        int pd = atomicAdd(&cd[kd >> 10], 1);
        ebd[pd] = (s << 10) | (kd & 1023);
        int ks = rb + s;
        int ps = atomicAdd(&cs[ks >> 10], 1);
        ebs[ps] = ks & 1023;
    }
}

// ---- PB: per bucket — exact histogram -> row_ptr/rs, then CSR scatter ----
__global__ __launch_bounds__(1024) void pb_kernel(const int* __restrict__ scanv, int nb, int RE,
                                                  const int* __restrict__ ebd,
                                                  const int* __restrict__ ebs,
                                                  int* __restrict__ row_ptr,
                                                  float* __restrict__ rs_in,
                                                  float* __restrict__ rs_out,
                                                  int* __restrict__ esrc) {
    __shared__ int cnt[BK];
    __shared__ int cur[BK];
    int t = threadIdx.x;
    bool dside = blockIdx.x < NBKT;
    int k = dside ? blockIdx.x : blockIdx.x - NBKT;
    int half = dside ? 0 : NBKT;
    int segbeg = scanv[(half + k) * nb];
    int segend = (k == NBKT - 1) ? (dside ? RE : 2 * RE) : scanv[(half + k + 1) * nb];
    if (!dside) { segbeg -= RE; segend -= RE; }
    cnt[t] = 0;
    __syncthreads();
    const int* __restrict__ eb = dside ? ebd : ebs;
    for (int e = segbeg + t; e < segend; e += 1024)
        atomicAdd(&cnt[eb[e] & 1023], 1);
    __syncthreads();
    int slot = k * BK + t;
    int c = cnt[t];
    if (dside) {
        cur[t] = c;
        __syncthreads();
        for (int off = 1; off < 1024; off <<= 1) {
            int u = (t >= off) ? cur[t - off] : 0;
            __syncthreads();
            cur[t] += u;
            __syncthreads();
        }
        int excl = cur[t] - c;
        if (slot < M) {
            row_ptr[slot] = segbeg + excl;
            rs_in[slot] = rsqrtf((float)(c + 1));
        }
        if (blockIdx.x == NBKT - 1 && t == 0) row_ptr[M] = RE;
        __syncthreads();
        cur[t] = segbeg + excl;
        __syncthreads();
        for (int e = segbeg + t; e < segend; e += 1024) {
            int v = eb[e];
            int pos = atomicAdd(&cur[v & 1023], 1);
            esrc[pos] = v >> 10;
        }
    } else {
        if (slot < M) rs_out[slot] = rsqrtf((float)(c + 1));
    }
}

// ---- pack per-edge coeff: esrc[i] = src | fp16(rs_out_r[src]) << 16 ----
__global__ void pack_kernel(unsigned int* __restrict__ esrc, const float* __restrict__ rs_out,
                            const int* __restrict__ row_ptr, int RE) {
    int i = blockIdx.x * 256 + threadIdx.x;
    if (i >= RE) return;
    int rp1 = row_ptr[N], rp2 = row_ptr[2 * N];
    int r = (i >= rp1) + (i >= rp2);
    unsigned s = esrc[i];
    __half h = __float2half_rn(rs_out[r * N + s]);
    esrc[i] = s | ((unsigned)__half_as_ushort(h) << 16);
}

// ---- fused 3-relation fp16 gather (R6 structure): one full wave per node,
// half2/lane rows (256B per gathered row), 4-way unrolled edge loop. ----
__global__ __launch_bounds__(256) void gather_kernel(const __half2* __restrict__ X2,
                                                     const float* __restrict__ rs_in,
                                                     const float* __restrict__ rs_out,
                                                     const int* __restrict__ row_ptr,
                                                     const unsigned int* __restrict__ esrc,
                                                     __half2* __restrict__ Z2) {
    int n = blockIdx.x * 4 + (threadIdx.x >> 6);
    if (n >= N) return;
    int lane = threadIdx.x & 63;
    float2 xn = __half22float2(X2[(long)n * 64 + lane]);
#pragma unroll
    for (int r = 0; r < R; r++) {
        int key = r * N + n;
        float ax = 0.f, ay = 0.f;
        int beg = row_ptr[key], end = row_ptr[key + 1];
        int e = beg;
        for (; e + 4 <= end; e += 4) {
            unsigned u0 = esrc[e], u1 = esrc[e + 1], u2 = esrc[e + 2], u3 = esrc[e + 3];
            float c0 = __half2float(__ushort_as_half((unsigned short)(u0 >> 16)));
            float c1 = __half2float(__ushort_as_half((unsigned short)(u1 >> 16)));
            float c2 = __half2float(__ushort_as_half((unsigned short)(u2 >> 16)));
            float c3 = __half2float(__ushort_as_half((unsigned short)(u3 >> 16)));
            float2 y0 = __half22float2(X2[(long)(u0 & 0xffffu) * 64 + lane]);
            float2 y1 = __half22float2(X2[(long)(u1 & 0xffffu) * 64 + lane]);
            float2 y2 = __half22float2(X2[(long)(u2 & 0xffffu) * 64 + lane]);
            float2 y3 = __half22float2(X2[(long)(u3 & 0xffffu) * 64 + lane]);
            ax += c0 * y0.x + c1 * y1.x + c2 * y2.x + c3 * y3.x;
            ay += c0 * y0.y + c1 * y1.y + c2 * y2.y + c3 * y3.y;
        }
        for (; e < end; e++) {
            unsigned u = esrc[e];
            float c = __half2float(__ushort_as_half((unsigned short)(u >> 16)));
            float2 y = __half22float2(X2[(long)(u & 0xffffu) * 64 + lane]);
            ax += c * y.x; ay += c * y.y;
        }
        float cn = rs_out[key];                 // self-loop, fp32 coeff
        ax += cn * xn.x; ay += cn * xn.y;
        float ri = rs_in[key];
        Z2[(long)n * 192 + r * 64 + lane] = __floats2half2_rn(ri * ax, ri * ay);
    }
}

// ---- MFMA GEMM: out[N,NT*32] = bias + Z16[N,384] @ W; A-frags direct from Z16
// rows (contiguous 16B per lane), B-frags from repacked F. 32x32x16 f16 MFMA.
// C/D map: col=lane&31, row=(reg&3)+8*(reg>>2)+4*(lane>>5)  [m74/m101 verified]
template <int NT, bool H16OUT>
__global__ __launch_bounds__(256) void mfma_gemm_kernel(const __half* __restrict__ Z16,
                                                        const __half* __restrict__ F,
                                                        const float* __restrict__ bias,
                                                        void* __restrict__ outp) {
    int wave = threadIdx.x >> 6, lane = threadIdx.x & 63;
    int m0 = blockIdx.x * 128 + wave * 32;
    int mrow = m0 + (lane & 31);
    int mr = min(mrow, N - 1);
    const half8* A = (const half8*)(Z16 + (long)mr * 384 + (lane >> 5) * 8);  // +2 per kb
    const half8* B = (const half8*)F;                                          // (nt*KB+kb)*64+lane
    floatx16 acc[NT];
#pragma unroll
    for (int i = 0; i < NT; i++)
#pragma unroll
        for (int j = 0; j < 16; j++) acc[i][j] = 0.f;

    half8 a = A[0];
    for (int kb = 0; kb < KB; kb++) {
        half8 an = (kb < KB - 1) ? A[(kb + 1) * 2] : a;
#pragma unroll
        for (int nt = 0; nt < NT; nt++) {
            half8 b = B[(nt * KB + kb) * 64 + lane];
            acc[nt] = __builtin_amdgcn_mfma_f32_32x32x16_f16(a, b, acc[nt], 0, 0, 0);
        }
        a = an;
    }

    float bv[NT];
#pragma unroll
    for (int nt = 0; nt < NT; nt++) bv[nt] = bias[nt * 32 + (lane & 31)];
    int rbase = m0 + 4 * (lane >> 5);
    int col0 = lane & 31;
#pragma unroll
    for (int nt = 0; nt < NT; nt++) {
#pragma unroll
        for (int reg = 0; reg < 16; reg++) {
            int row = rbase + (reg & 3) + 8 * (reg >> 2);
            if (row < N) {
                float v = acc[nt][reg] + bv[nt];
                if (H16OUT) {
                    v = fmaxf(v, 0.f);
                    ((__half*)outp)[(long)row * (NT * 32) + nt * 32 + col0] = __float2half_rn(v);
                } else {
                    ((float*)outp)[(long)row * (NT * 32) + nt * 32 + col0] = v;
                }
            }
        }
    }
}

extern "C" void kernel_launch(void* const* d_in, const int* in_sizes, int n_in,
                              void* d_out, int out_size, void* d_ws, size_t ws_size,
                              hipStream_t stream) {
    const float* x  = (const float*)d_in[0];
    const int*  src = (const int*)d_in[1];
    const int*  dst = (const int*)d_in[2];
    const float* W1 = (const float*)d_in[3];   // [384][128]
    const float* b1 = (const float*)d_in[4];
    const float* W2 = (const float*)d_in[5];   // [384][64]
    const float* b2 = (const float*)d_in[6];
    float* out = (float*)d_out;
    const int E  = in_sizes[1] / R;
    const int RE = in_sizes[1];
    const int nb = (RE + CHUNK - 1) / CHUNK;
    const int L  = 2 * NBKT * nb;
    const int nb1 = (L + 1023) / 1024;

    char* ws = (char*)d_ws;
    size_t off = 0;
    auto alloc = [&](size_t bytes) -> void* {
        void* p = ws + off;
        off += (bytes + 255) & ~(size_t)255;
        return p;
    };
    float* bsum1    = (float*)alloc(HID * 4);
    float* bsum2    = (float*)alloc(OUT * 4);
    float* rs_in    = (float*)alloc((size_t)M * 4);
    float* rs_out   = (float*)alloc((size_t)M * 4);
    int*   row_ptr  = (int*)alloc((size_t)(M + 1) * 4);
    int*   bh       = (int*)alloc((size_t)L * 4);
    int*   scanv    = (int*)alloc((size_t)L * 4);
    int*   partials = (int*)alloc((size_t)nb1 * 4);
    int*   esrc     = (int*)alloc((size_t)RE * 4);
    __half* F1      = (__half*)alloc((size_t)4 * KB * 64 * 8 * 2);
    __half* F2      = (__half*)alloc((size_t)2 * KB * 64 * 8 * 2);
    // region A: ebd+ebs (19.2MB) during build, Z16 (38.4MB) afterwards
    char*  regA     = (char*)alloc((size_t)N * 384 * 2);
    int*   ebd      = (int*)regA;
    int*   ebs      = (int*)(regA + (size_t)RE * 4);
    __half* Z16     = (__half*)regA;
    __half* x16     = (__half*)alloc((size_t)N * IN * 2);
    __half* H16     = (__half*)alloc((size_t)N * HID * 2);

    bsum_kernel<<<1, 128, 0, stream>>>(b1, b2, bsum1, bsum2);
    cvt_kernel<<<(N * IN / 4 + 255) / 256, 256, 0, stream>>>(
        (const float4*)x, (uint2*)x16, N * IN / 4);
    wpack_kernel<<<(6 * KB * 64 + 255) / 256, 256, 0, stream>>>(W1, W2, F1, F2);
    p1_kernel<<<nb, 256, 0, stream>>>(src, dst, E, RE, nb, bh);
    scan1_kernel<<<nb1, 1024, 0, stream>>>(bh, scanv, partials, L);
    scan2_kernel<<<1, 256, 0, stream>>>(partials, nb1);
    scan3_kernel<<<(L + 255) / 256, 256, 0, stream>>>(scanv, partials, L);
    p3_kernel<<<nb, 256, 0, stream>>>(src, dst, E, RE, nb, scanv, ebd, ebs);
    pb_kernel<<<2 * NBKT, 1024, 0, stream>>>(scanv, nb, RE, ebd, ebs,
                                             row_ptr, rs_in, rs_out, esrc);
    pack_kernel<<<(RE + 255) / 256, 256, 0, stream>>>(
        (unsigned int*)esrc, rs_out, row_ptr, RE);

    const int ab  = (N + 3) / 4;              // 12500 gather blocks
    const int ggb = (N + 127) / 128;          // 391 gemm blocks

    // layer 1: Z = gather(x16); H16 = fp16(relu(bsum1 + Z @ W1))
    gather_kernel<<<ab, 256, 0, stream>>>((const __half2*)x16, rs_in, rs_out,
                                          row_ptr, (const unsigned int*)esrc,
                                          (__half2*)Z16);
    mfma_gemm_kernel<4, true><<<ggb, 256, 0, stream>>>(Z16, F1, bsum1, H16);
    // layer 2: Z = gather(H16); out = bsum2 + Z @ W2
    gather_kernel<<<ab, 256, 0, stream>>>((const __half2*)H16, rs_in, rs_out,
                                          row_ptr, (const unsigned int*)esrc,
                                          (__half2*)Z16);
    mfma_gemm_kernel<2, false><<<ggb, 256, 0, stream>>>(Z16, F2, bsum2, out);
}